// Round 6
// baseline (101.066 us; speedup 1.0000x reference)
//
#include <hip/hip_runtime.h>

// NEUROPULS unitary mesh, N=256 — precomputed fused stage operators.
// R5 post-mortem: mesh kernel issue-bound at 1 wave/SIMD; ~half the issue was
// 4x __sincosf per lane per stage, recomputed identically by all 256 blocks.
// Fix: (1) prep kernel computes the FUSED 2x2 operator F = MMI*P(theta)*MMI
// per (stage, even-pair) ONCE into d_ws (512 KB, L2-broadcast to all waves);
// (2) mesh kernel stage = 4 coalesced dwordx4 loads (depth-2 prefetch) +
// 32-FMA fused matvec + crossing. Zero transcendentals in the hot loop.
//
// F algebra (AT=a*t, AR=a*r real):  F = M P M,  M=[[AT, i AR],[i AR, AT]]
//   F00 = AT^2 e^{i thx} - AR^2 e^{i thy}
//   F01 = F10 = i AT AR (e^{i thx} + e^{i thy})
//   F11 = AT^2 e^{i thy} - AR^2 e^{i thx}
// ws layout: stage s (1..128) at float offset (s-1)*1024; pair p: 8 floats
//   {F00r,F00i,F01r,F01i, F11r,F11i, 0,0}. Mesh reads one pad stage (129) —
//   values unused, ws_size (256 MB) >> 129*4KB.

constexpr int N = 256;

__global__ __launch_bounds__(256)
void neuropuls_prep_kernel(const float* __restrict__ thetas, float* __restrict__ F)
{
    const int gid = blockIdx.x * 256 + threadIdx.x;   // 0..16383
    const int s   = 1 + (gid >> 7);                   // stage 1..128
    const int p   = gid & 127;                        // even-pair 0..127

    const float AT2 = 0.98f * 0.505f;                    // (a*t)^2
    const float AR2 = 0.98f * 0.495f;                    // (a*r)^2
    const float ATR = 0.98f * sqrtf(0.505f * 0.495f);    // a^2 * t * r

    const float thx = thetas[s * N + 2 * p];
    const float thy = thetas[s * N + 2 * p + 1];
    float sx, cx, sy, cy;
    __sincosf(thx, &sx, &cx);
    __sincosf(thy, &sy, &cy);

    float4 w0, w1;
    w0.x = AT2 * cx - AR2 * cy;     // F00r
    w0.y = AT2 * sx - AR2 * sy;     // F00i
    w0.z = -ATR * (sx + sy);        // F01r
    w0.w =  ATR * (cx + cy);        // F01i
    w1.x = AT2 * cy - AR2 * cx;     // F11r
    w1.y = AT2 * sy - AR2 * sx;     // F11i
    w1.z = 0.f; w1.w = 0.f;

    float4* dst = (float4*)(F + (size_t)(s - 1) * 1024 + p * 8);
    dst[0] = w0;
    dst[1] = w1;
}

__global__ __launch_bounds__(64)
void neuropuls_mesh_kernel(const float* __restrict__ thetas,   // [130,256] fp32
                           const float* __restrict__ F,        // fused ops in ws
                           float* __restrict__ out)            // re[65536] || im[65536]
{
    const int lane = threadIdx.x;   // 0..63
    const int col  = blockIdx.x;    // 0..255

    const float BT = sqrtf(0.98f * 0.01f);    // CR a*sqrt(CT)
    const float BR = sqrtf(0.98f * 0.99f);    // CR a*sqrt(1-CT) == thru

    float vr[4] = {0.f, 0.f, 0.f, 0.f};
    float vi[4] = {0.f, 0.f, 0.f, 0.f};

    // arch0 = diag(exp(i*theta[0]))
    {
        const float th0 = thetas[col];
        float s0, c0;
        __sincosf(th0, &s0, &c0);
        const int r0 = col - 4 * lane;
        if (0 <= r0 && r0 < 4) { vr[r0] = c0; vi[r0] = s0; }
    }

    // lane owns even-pairs 2*lane, 2*lane+1 => 16 consecutive floats per stage
    const float4* fp = (const float4*)F + (lane << 2);

    auto fused_pair = [&](int x, int y, float4 f0, float4 f1) {
        float z0r = vr[x], z0i = vi[x], z1r = vr[y], z1i = vi[y];
        vr[x] = f0.x * z0r - f0.y * z0i + f0.z * z1r - f0.w * z1i;
        vi[x] = f0.x * z0i + f0.y * z0r + f0.z * z1i + f0.w * z1r;
        vr[y] = f0.z * z0r - f0.w * z0i + f1.x * z1r - f1.y * z1i;
        vi[y] = f0.z * z0i + f0.w * z0r + f1.x * z1i + f1.y * z1r;
    };
    auto crossing = [&]() {
        float pv3r = __shfl_up(vr[3], 1);
        float pv3i = __shfl_up(vi[3], 1);
        float nv0r = __shfl_down(vr[0], 1);
        float nv0i = __shfl_down(vi[0], 1);
        {   // internal odd pair (4t+1, 4t+2)
            float xr = vr[1], xi = vi[1], yr = vr[2], yi = vi[2];
            vr[1] = BT * xr - BR * yi;  vi[1] = BT * xi + BR * yr;
            vr[2] = BT * yr - BR * xi;  vi[2] = BT * yi + BR * xr;
        }
        {   // pair (4t-1, 4t): lane 0 row 0 = thru
            float yr = vr[0], yi = vi[0];
            float nr = BT * yr - BR * pv3i;
            float ni = BT * yi + BR * pv3r;
            vr[0] = (lane == 0) ? BR * yr : nr;
            vi[0] = (lane == 0) ? BR * yi : ni;
        }
        {   // pair (4t+3, 4t+4): lane 63 row 255 = thru
            float xr = vr[3], xi = vi[3];
            float nr = BT * xr - BR * nv0i;
            float ni = BT * xi + BR * nv0r;
            vr[3] = (lane == 63) ? BR * xr : nr;
            vi[3] = (lane == 63) ? BR * xi : ni;
        }
    };

    // depth-2 prefetch ping-pong: A = F[s], B = F[s+1], C in flight = F[s+2]
    float4 A0 = fp[0], A1 = fp[1], A2 = fp[2], A3 = fp[3];  fp += 256;
    float4 B0 = fp[0], B1 = fp[1], B2 = fp[2], B3 = fp[3];  fp += 256;

    #pragma unroll 2
    for (int s = 1; s <= 127; ++s) {   // crossing stages
        float4 C0 = fp[0], C1 = fp[1], C2 = fp[2], C3 = fp[3];  fp += 256; // F[s+2]; s=127 -> pad
        fused_pair(0, 1, A0, A1);
        fused_pair(2, 3, A2, A3);
        crossing();
        A0 = B0; A1 = B1; A2 = B2; A3 = B3;
        B0 = C0; B1 = C1; B2 = C2; B3 = C3;
    }

    // stage 128 (no crossing): A = F[128]
    fused_pair(0, 1, A0, A1);
    fused_pair(2, 3, A2, A3);

    // final phase layer theta[129]
    {
        const float4 th = *(const float4*)(thetas + 129 * N + 4 * lane);
        const float a[4] = {th.x, th.y, th.z, th.w};
        #pragma unroll
        for (int j = 0; j < 4; ++j) {
            float sn, cs;
            __sincosf(a[j], &sn, &cs);
            float r = vr[j], i = vi[j];
            vr[j] = cs * r - sn * i;
            vi[j] = cs * i + sn * r;
        }
    }

    // store PLANAR: real block then imag block, each row-major [row][col]
    #pragma unroll
    for (int j = 0; j < 4; ++j) {
        const int idx = (4 * lane + j) * N + col;
        out[idx]         = vr[j];
        out[N * N + idx] = vi[j];
    }
}

extern "C" void kernel_launch(void* const* d_in, const int* in_sizes, int n_in,
                              void* d_out, int out_size, void* d_ws, size_t ws_size,
                              hipStream_t stream)
{
    const float* thetas = (const float*)d_in[0];   // [130,256] fp32
    float* F   = (float*)d_ws;                     // 128 stages * 1024 floats (+1 pad stage read)
    float* out = (float*)d_out;                    // planar: re[65536] || im[65536]
    (void)in_sizes; (void)n_in; (void)out_size; (void)ws_size;

    neuropuls_prep_kernel<<<dim3(64), dim3(256), 0, stream>>>(thetas, F);
    neuropuls_mesh_kernel<<<dim3(256), dim3(64), 0, stream>>>(thetas, F, out);
}

// Round 7
// 85.427 us; speedup vs baseline: 1.1831x; 1.1831x over previous
//
#include <hip/hip_runtime.h>

// NEUROPULS unitary mesh, N=256 — ASSOCIATIVE SPLIT (K=2).
// R6 post-mortem: shared global F table = cross-XCD latency trap; serial
// chain must be fed from registers. R5's chain is issue-bound at 1 wave/SIMD
// x 128 serial stages. Fix: split the operator product in half:
//   A = (stages 1..64, each CR*MMI*P*MMI) * diag(e^{i th0})
//   B = P(th129) * MMI*P(th128)*MMI * (stages 65..127 with CR) * I
//   out = B * A   (256x256 complex matmul, fp32 vector, ~134 MFLOP)
// Both halves run concurrently: 512 blocks x 1 wave = 2 waves/CU.
// ws layout: Abuf = float2[256][256] (Abuf[c][k] = A[k][c], block-contiguous)
//            Bbuf = float2[256][256] (Bbuf[k][r] = B[r][k], block-contiguous)

constexpr int N = 256;

__global__ __launch_bounds__(64)
void neuropuls_chain_kernel(const float* __restrict__ thetas,  // [130,256] fp32
                            float2* __restrict__ Abuf,         // [c][k]
                            float2* __restrict__ Bbuf)         // [k][r]
{
    const int lane = threadIdx.x;          // 0..63
    const bool isB = blockIdx.x >= 256;
    const int col  = blockIdx.x & 255;     // column of A, or k-index (column) of B

    const float AT = sqrtf(0.98f * 0.505f);   // MMI a*t
    const float AR = sqrtf(0.98f * 0.495f);   // MMI a*r
    const float BT = sqrtf(0.98f * 0.01f);    // CR a*sqrt(CT)
    const float BR = sqrtf(0.98f * 0.99f);    // CR thru

    float vr[4] = {0.f, 0.f, 0.f, 0.f};
    float vi[4] = {0.f, 0.f, 0.f, 0.f};

    // start state: chainA = diag(e^{i th0}) column; chainB = identity column
    {
        const int r0 = col - 4 * lane;
        if (0 <= r0 && r0 < 4) {
            if (isB) { vr[r0] = 1.f; vi[r0] = 0.f; }
            else {
                float s0, c0;
                __sincosf(thetas[col], &s0, &c0);
                vr[r0] = c0; vi[r0] = s0;
            }
        }
    }

    const int s0     = isB ? 65 : 1;     // first stage of this half
    const int nCross = isB ? 63 : 64;    // crossing stages: A: 1..64, B: 65..127

    const float* tp = thetas + s0 * N + 4 * lane;

    auto mmi_pair = [&](int x, int y) {
        float xr = vr[x], xi = vi[x], yr = vr[y], yi = vi[y];
        vr[x] = AT * xr - AR * yi;  vi[x] = AT * xi + AR * yr;
        vr[y] = AT * yr - AR * xi;  vi[y] = AT * yi + AR * xr;
    };
    auto phase4c = [&](const float sn[4], const float cs[4]) {
        #pragma unroll
        for (int j = 0; j < 4; ++j) {
            float r = vr[j], i = vi[j];
            vr[j] = cs[j] * r - sn[j] * i;
            vi[j] = cs[j] * i + sn[j] * r;
        }
    };
    auto crossing = [&]() {
        float pv3r = __shfl_up(vr[3], 1);
        float pv3i = __shfl_up(vi[3], 1);
        float nv0r = __shfl_down(vr[0], 1);
        float nv0i = __shfl_down(vi[0], 1);
        {   // internal odd pair (4t+1, 4t+2)
            float xr = vr[1], xi = vi[1], yr = vr[2], yi = vi[2];
            vr[1] = BT * xr - BR * yi;  vi[1] = BT * xi + BR * yr;
            vr[2] = BT * yr - BR * xi;  vi[2] = BT * yi + BR * xr;
        }
        {   // pair (4t-1, 4t): lane 0 row 0 = thru
            float yr = vr[0], yi = vi[0];
            float nr = BT * yr - BR * pv3i;
            float ni = BT * yi + BR * pv3r;
            vr[0] = (lane == 0) ? BR * yr : nr;
            vi[0] = (lane == 0) ? BR * yi : ni;
        }
        {   // pair (4t+3, 4t+4): lane 63 row 255 = thru
            float xr = vr[3], xi = vi[3];
            float nr = BT * xr - BR * nv0i;
            float ni = BT * xi + BR * nv0r;
            vr[3] = (lane == 63) ? BR * xr : nr;
            vi[3] = (lane == 63) ? BR * xi : ni;
        }
    };
    auto sincos4 = [](float4 th, float sn[4], float cs[4]) {
        __sincosf(th.x, &sn[0], &cs[0]);
        __sincosf(th.y, &sn[1], &cs[1]);
        __sincosf(th.z, &sn[2], &cs[2]);
        __sincosf(th.w, &sn[3], &cs[3]);
    };

    // software pipeline (R5 pattern): snA = sincos(theta[s]), thN = theta[s+1]
    float snA[4], csA[4];
    float4 thN;
    {
        float4 t1 = *(const float4*)tp;  tp += N;   // theta[s0]
        thN = *(const float4*)tp;        tp += N;   // theta[s0+1]
        sincos4(t1, snA, csA);
    }

    // crossing stages s0 .. s0+nCross-2 (last crossing stage after the loop)
    #pragma unroll 2
    for (int it = 0; it < nCross - 1; ++it) {
        float4 thNN = *(const float4*)tp;  tp += N;   // theta[s+2], max theta[s0+nCross] <= 129
        float snB[4], csB[4];
        sincos4(thN, snB, csB);            // off the serial chain
        mmi_pair(0, 1); mmi_pair(2, 3);
        phase4c(snA, csA);
        mmi_pair(0, 1); mmi_pair(2, 3);
        crossing();
        #pragma unroll
        for (int j = 0; j < 4; ++j) { snA[j] = snB[j]; csA[j] = csB[j]; }
        thN = thNN;
    }

    // last crossing stage (A: s=64, B: s=127) with coefficients snA
    mmi_pair(0, 1); mmi_pair(2, 3);
    phase4c(snA, csA);
    mmi_pair(0, 1); mmi_pair(2, 3);
    crossing();

    if (isB) {
        // stage 128 (no crossing): thN = theta[128]
        float sn[4], cs[4];
        sincos4(thN, sn, cs);
        mmi_pair(0, 1); mmi_pair(2, 3);
        phase4c(sn, cs);
        mmi_pair(0, 1); mmi_pair(2, 3);
        // final phase layer theta[129]
        float4 thF = *(const float4*)(thetas + 129 * N + 4 * lane);
        sincos4(thF, sn, cs);
        phase4c(sn, cs);
    }

    // write: both halves store their column contiguously:
    //   A: Abuf[col][k] (k = 4*lane+j);  B: Bbuf[col][r] (r = 4*lane+j)
    float2* dst = (isB ? Bbuf : Abuf) + col * N + 4 * lane;
    #pragma unroll
    for (int j = 0; j < 4; ++j) dst[j] = make_float2(vr[j], vi[j]);
}

// out[r][c] = sum_k B[r][k] * A[k][c]; block = column c, thread = row r.
__global__ __launch_bounds__(256)
void neuropuls_combine_kernel(const float2* __restrict__ Abuf,  // [c][k]
                              const float2* __restrict__ Bbuf,  // [k][r]
                              float* __restrict__ out)          // re[65536] || im[65536]
{
    __shared__ float2 Acol[N];
    const int c = blockIdx.x;
    const int r = threadIdx.x;

    Acol[r] = Abuf[c * N + r];     // stage column c of A (2 KB), coalesced
    __syncthreads();

    float accr = 0.f, acci = 0.f;
    #pragma unroll 8
    for (int k = 0; k < N; ++k) {
        float2 b = Bbuf[k * N + r];   // coalesced across threads
        float2 a = Acol[k];           // LDS broadcast (same addr all lanes)
        accr += b.x * a.x - b.y * a.y;
        acci += b.x * a.y + b.y * a.x;
    }

    out[r * N + c]         = accr;
    out[N * N + r * N + c] = acci;
}

extern "C" void kernel_launch(void* const* d_in, const int* in_sizes, int n_in,
                              void* d_out, int out_size, void* d_ws, size_t ws_size,
                              hipStream_t stream)
{
    const float* thetas = (const float*)d_in[0];   // [130,256] fp32
    float2* Abuf = (float2*)d_ws;                  // 512 KB
    float2* Bbuf = Abuf + N * N;                   // 512 KB
    float* out = (float*)d_out;                    // planar: re[65536] || im[65536]
    (void)in_sizes; (void)n_in; (void)out_size; (void)ws_size;

    neuropuls_chain_kernel<<<dim3(512), dim3(64), 0, stream>>>(thetas, Abuf, Bbuf);
    neuropuls_combine_kernel<<<dim3(256), dim3(256), 0, stream>>>(Abuf, Bbuf, out);
}